// Round 10
// baseline (150.661 us; speedup 1.0000x reference)
//
#include <hip/hip_runtime.h>
#include <hip/hip_bf16.h>

typedef unsigned short u16;
typedef __bf16 bf16x8 __attribute__((ext_vector_type(8)));
typedef float f32x4 __attribute__((ext_vector_type(4)));

#define S_LEN 2048
#define NH 16
#define NB 2
#define HEAD_ELEMS (NB * NH * S_LEN * 64)
#define BH_ELEMS (S_LEN * 64)   // 131072 elems per (b,h)

#if __has_builtin(__builtin_amdgcn_exp2f)
#define EXP2(x) __builtin_amdgcn_exp2f(x)
#else
#define EXP2(x) exp2f(x)
#endif

// 1/sqrt(64) * log2(e), folded into Wq. Scores come out in log2 units.
#define QSCALE 0.180336880f
#define SHIFT2 30.0f

// async global->LDS, 16B per lane: LDS dest = uniform base + lane*16,
// global src = per-lane. Our Kp/Vt2 DRAM tiles are already lane-permuted,
// so the LDS image == DRAM tile and fragment reads stay lane-linear.
#define GLDS16(g, l) __builtin_amdgcn_global_load_lds( \
    (const __attribute__((address_space(1))) void*)(g), \
    (__attribute__((address_space(3))) void*)(l), 16, 0, 0)

__device__ __forceinline__ bf16x8 pack8(float4 a, float4 b, float sc) {
    union { bf16x8 v; __hip_bfloat162 h[4]; } r;
    r.h[0] = __float22bfloat162_rn(make_float2(a.x * sc, a.y * sc));
    r.h[1] = __float22bfloat162_rn(make_float2(a.z * sc, a.w * sc));
    r.h[2] = __float22bfloat162_rn(make_float2(b.x * sc, b.y * sc));
    r.h[3] = __float22bfloat162_rn(make_float2(b.z * sc, b.w * sc));
    return r.v;
}

// ---------------- fused projections (byte-identical to verified R9) --------
__global__ __launch_bounds__(256) void proj_fused(
    const float* __restrict__ kin, const float* __restrict__ qin,
    const float* __restrict__ vin,
    const float* __restrict__ Wk, const float* __restrict__ Wq,
    const float* __restrict__ Wv,
    u16* __restrict__ Kh, u16* __restrict__ Qh, u16* __restrict__ Vt)
{
    __shared__ __align__(16) u16 Yld[8 * 16 * 72];   // kq uses all; v uses first 64*72
    __shared__ __align__(16) u16 Stage[16 * 512];    // kq x-tile 16KB; v uses first 8KB

    const int tid = threadIdx.x;
    const int wave = tid >> 6;
    const int lane = tid & 63;
    const int quad = lane >> 4;
    const int l15 = lane & 15;
    const int bid = blockIdx.x;

    if (bid < 1024) {
        // ---------------- K/Q projection ----------------
        const int stile = bid & 255;
        const int p = (bid >> 8) & 1;
        const int hh = bid >> 9;
        const long row0 = (long)stile * 16;
        const int b = (int)(row0 >> 11);
        const int s0 = (int)(row0 & 2047);

        const float* X = p ? qin : kin;
        const float* W = p ? Wq : Wk;
        const float sc = p ? QSCALE : 1.0f;

        // stage x: 16 rows x 512 cols (this hh half) -> bf16 LDS, swizzled.
        #pragma unroll
        for (int it = 0; it < 4; ++it) {
            int chunk = tid + it * 256;              // 0..1023
            int row = chunk >> 6, col8 = chunk & 63;
            const float* gp = X + (row0 + row) * 1024 + hh * 512 + col8 * 8;
            bf16x8 v = pack8(*(const float4*)gp, *(const float4*)(gp + 4), 1.0f);
            int byteoff = (row * 1024 + col8 * 16) ^ ((row & 7) << 4);
            *(bf16x8*)((char*)Stage + byteoff) = v;
        }

        bf16x8 wf[4][2];
        #pragma unroll
        for (int nt = 0; nt < 4; ++nt) {
            const float* wr = W + (nt * 16 + l15) * 64 + quad * 8;
            wf[nt][0] = pack8(*(const float4*)(wr),      *(const float4*)(wr + 4),  sc);
            wf[nt][1] = pack8(*(const float4*)(wr + 32), *(const float4*)(wr + 36), sc);
        }
        __syncthreads();

        #pragma unroll
        for (int hp = 0; hp < 2; ++hp) {
            const int hl = wave * 2 + hp;            // 0..7
            int acol = l15 * 1024 + hl * 128 + quad * 16;
            int swz = (l15 & 7) << 4;
            bf16x8 a0 = *(const bf16x8*)((const char*)Stage + (acol ^ swz));
            bf16x8 a1 = *(const bf16x8*)((const char*)Stage + ((acol + 64) ^ swz));
            #pragma unroll
            for (int nt = 0; nt < 4; ++nt) {
                f32x4 c = (f32x4){0.f, 0.f, 0.f, 0.f};
                c = __builtin_amdgcn_mfma_f32_16x16x32_bf16(a0, wf[nt][0], c, 0, 0, 0);
                c = __builtin_amdgcn_mfma_f32_16x16x32_bf16(a1, wf[nt][1], c, 0, 0, 0);
                union { __hip_bfloat162 h2; u16 u[2]; } x01, x23;
                x01.h2 = __float22bfloat162_rn(make_float2(c[0], c[1]));
                x23.h2 = __float22bfloat162_rn(make_float2(c[2], c[3]));
                int base = (hl * 16 + quad * 4) * 72 + nt * 16 + l15;
                Yld[base]       = x01.u[0];
                Yld[base + 72]  = x01.u[1];
                Yld[base + 144] = x23.u[0];
                Yld[base + 216] = x23.u[1];
            }
        }
        __syncthreads();

        if (p) {
            // Q: baseline row-major writes
            #pragma unroll
            for (int it = 0; it < 4; ++it) {
                int idx = tid + it * 256;            // 0..1023
                int eg = idx & 7, s = (idx >> 3) & 15, hl = idx >> 7;
                int bh = b * NH + hh * 8 + hl;
                *(float4*)(Qh + ((long)bh * S_LEN + s0 + s) * 64 + eg * 8) =
                    *(const float4*)&Yld[(hl * 16 + s) * 72 + eg * 8];
            }
        } else {
            // K: permuted Kp writes (16B chunk per thread, e contiguous)
            #pragma unroll
            for (int it = 0; it < 4; ++it) {
                int idx = tid + it * 256;            // 0..1023
                int eg = idx & 7, s = (idx >> 3) & 15, hl = idx >> 7;
                int bh = b * NH + hh * 8 + hl;
                int sg = s0 + s;                     // global s row within batch
                int kt = sg >> 6, c = (sg >> 5) & 1, rp = sg & 31;
                int nn = (rp >> 2) & 1;
                int l15p = ((rp >> 3) << 2) | (rp & 3);
                int j = eg >> 2, qd = eg & 3;
                long off = (long)bh * BH_ELEMS
                         + (long)((((kt * 2 + c) * 2 + nn) * 2 + j) * 512 + (qd * 16 + l15p) * 8);
                *(float4*)(Kh + off) = *(const float4*)&Yld[(hl * 16 + s) * 72 + eg * 8];
            }
        }
    } else {
        // ---------------- V projection (permuted Vt2 out) ----------------
        const int vid = bid - 1024;
        const long row0 = (long)(vid & 63) * 64;
        const int b = (int)(row0 >> 11);
        const int s0 = (int)(row0 & 2047);
        const int h = vid >> 6;
        const int bh = b * NH + h;
        const int kt = s0 >> 6;                      // this block covers exactly one kt tile

        #pragma unroll
        for (int it = 0; it < 4; ++it) {
            int chunk = tid + it * 256;              // 0..1023
            int row = chunk >> 4, c16 = chunk & 15;
            const float* gp = vin + (row0 + row) * 1024 + h * 64 + c16 * 4;
            float4 f = *(const float4*)gp;
            union { __hip_bfloat162 h2[2]; unsigned long long u; } pk;
            pk.h2[0] = __float22bfloat162_rn(make_float2(f.x, f.y));
            pk.h2[1] = __float22bfloat162_rn(make_float2(f.z, f.w));
            int byteoff = (row * 128 + c16 * 8) ^ ((row & 7) << 4);
            *(unsigned long long*)((char*)Stage + byteoff) = pk.u;
        }

        bf16x8 wf[4][2];
        #pragma unroll
        for (int dt = 0; dt < 4; ++dt) {
            const float* wr = Wv + (dt * 16 + l15) * 64 + quad * 8;
            wf[dt][0] = pack8(*(const float4*)(wr),      *(const float4*)(wr + 4),  1.0f);
            wf[dt][1] = pack8(*(const float4*)(wr + 32), *(const float4*)(wr + 36), 1.0f);
        }
        __syncthreads();

        int vcol = (wave * 16 + l15) * 128 + quad * 16;
        int vswz = (l15 & 7) << 4;
        bf16x8 x0 = *(const bf16x8*)((const char*)Stage + (vcol ^ vswz));
        bf16x8 x1 = *(const bf16x8*)((const char*)Stage + ((vcol + 64) ^ vswz));

        #pragma unroll
        for (int dt = 0; dt < 4; ++dt) {
            f32x4 c = (f32x4){0.f, 0.f, 0.f, 0.f};
            c = __builtin_amdgcn_mfma_f32_16x16x32_bf16(wf[dt][0], x0, c, 0, 0, 0);
            c = __builtin_amdgcn_mfma_f32_16x16x32_bf16(wf[dt][1], x1, c, 0, 0, 0);
            int base = (dt * 16 + quad * 4) * 72 + wave * 16 + l15;
            union { __hip_bfloat162 h2; u16 u[2]; } x01, x23;
            x01.h2 = __float22bfloat162_rn(make_float2(c[0], c[1]));
            x23.h2 = __float22bfloat162_rn(make_float2(c[2], c[3]));
            Yld[base]       = x01.u[0];
            Yld[base + 72]  = x01.u[1];
            Yld[base + 144] = x23.u[0];
            Yld[base + 216] = x23.u[1];
        }
        __syncthreads();

        u16* dstb = Vt + (long)bh * BH_ELEMS;
        #pragma unroll
        for (int it = 0; it < 2; ++it) {
            int idx = tid + it * 256;                // 0..511
            int sg = idx & 7, e_row = idx >> 3;
            int c = sg >> 2, lhi = sg & 3;
            int dt = e_row >> 4, l15p = e_row & 15;
            long off = (long)(((kt * 2 + c) * 4 + dt) * 512 + (lhi * 16 + l15p) * 8);
            *(float4*)(dstb + off) = *(const float4*)&Yld[e_row * 72 + sg * 8];
        }
    }
}

// ---------------- attention: shared-kt waves + 2-phase gload_lds pipeline --
// R10 restructure (T3-minimum, plain HIP):
//  - All 4 waves share each kt tile; wave w owns q-rows [q0+w*16, +16) for
//    ALL kt. Q fragment in 8 VGPRs (Qld deleted); oacc 64->16 VGPR; the
//    entire cross-wave O/l merge epilogue (Old/lbc + 8 barriers) is GONE.
//  - K/V double-buffered in LDS (2 x 16KB) via global_load_lds (DRAM tiles
//    are lane-permuted since R6, so linear LDS image == fragment layout).
//    Per tile: stage(next) -> compute(cur) -> __syncthreads (drains vmcnt:
//    stage loads had the whole compute phase to land -> latency hidden).
//  - XCD decode + SHIFT2 fold kept from R9 (verified).
__global__ __launch_bounds__(256, 4) void attn_kernel(
    const u16* __restrict__ Qh, const u16* __restrict__ Kh,
    const u16* __restrict__ Vt, float* __restrict__ out)
{
    __shared__ __align__(16) u16 KV[2][8192];   // [buf][K 4096 elems | V 4096 elems]

    const int tid = threadIdx.x;
    const int wave = tid >> 6;
    const int lane = tid & 63;
    const int quad = lane >> 4;
    const int l15 = lane & 15;
    // XCD-aware bijective decode (1024 blocks, 8 XCDs)
    const int bid = blockIdx.x;
    const int xcd = bid & 7;
    const int i = bid >> 3;                          // 0..127
    const int bh = xcd * 4 + (i >> 5);               // 4 bh per XCD
    const int qb = i & 31;
    const int b = bh >> 4, h = bh & 15;
    const int q0 = qb * 64;
    const u16* kb = Kh + (long)bh * BH_ELEMS;
    const u16* vb = Vt + (long)bh * BH_ELEMS;

    // Q fragment for this wave's 16 q-rows -> registers (once)
    bf16x8 qf0, qf1;
    {
        const u16* qp = Qh + ((long)bh * S_LEN + q0 + wave * 16 + l15) * 64 + quad * 8;
        qf0 = *(const bf16x8*)(qp);
        qf1 = *(const bf16x8*)(qp + 32);
    }

    // staging split: waves 0/1 -> K halves, waves 2/3 -> V halves (4KB each)
    const u16* gsk = ((wave & 2) ? vb : kb) + ((wave & 1) << 11) + lane * 8;
    const int ldsoff = ((wave & 2) ? 4096 : 0) + ((wave & 1) << 11);

    f32x4 oacc[4];
    #pragma unroll
    for (int dt = 0; dt < 4; ++dt) oacc[dt] = (f32x4){0.f, 0.f, 0.f, 0.f};
    float rs = 0.f;

    // prologue: stage tile 0 into buf 0
    {
        const u16* g = gsk;
        u16* l = &KV[0][ldsoff];
        #pragma unroll
        for (int ii = 0; ii < 4; ++ii)
            GLDS16(g + ii * 512, l + ii * 512);
    }
    __syncthreads();

    int buf = 0;
    #pragma unroll 1
    for (int t = 0; t < S_LEN / 64; ++t) {
        if (t < S_LEN / 64 - 1) {                    // stage next tile -> buf^1
            const u16* g = gsk + (t + 1) * 4096;
            u16* l = &KV[buf ^ 1][ldsoff];
            #pragma unroll
            for (int ii = 0; ii < 4; ++ii)
                GLDS16(g + ii * 512, l + ii * 512);
        }

        const u16* Kl = &KV[buf][0];
        const u16* Vl = &KV[buf][4096];
        #pragma unroll
        for (int c = 0; c < 2; ++c) {
            bf16x8 kf[2][2], vf[4];
            #pragma unroll
            for (int nn = 0; nn < 2; ++nn) {
                kf[nn][0] = *(const bf16x8*)(Kl + ((c * 2 + nn) * 2 + 0) * 512 + lane * 8);
                kf[nn][1] = *(const bf16x8*)(Kl + ((c * 2 + nn) * 2 + 1) * 512 + lane * 8);
            }
            #pragma unroll
            for (int dt = 0; dt < 4; ++dt)
                vf[dt] = *(const bf16x8*)(Vl + (c * 4 + dt) * 512 + lane * 8);

            f32x4 s0 = (f32x4){-SHIFT2, -SHIFT2, -SHIFT2, -SHIFT2};
            f32x4 s1 = (f32x4){-SHIFT2, -SHIFT2, -SHIFT2, -SHIFT2};
            s0 = __builtin_amdgcn_mfma_f32_16x16x32_bf16(kf[0][0], qf0, s0, 0, 0, 0);
            s0 = __builtin_amdgcn_mfma_f32_16x16x32_bf16(kf[0][1], qf1, s0, 0, 0, 0);
            s1 = __builtin_amdgcn_mfma_f32_16x16x32_bf16(kf[1][0], qf0, s1, 0, 0, 0);
            s1 = __builtin_amdgcn_mfma_f32_16x16x32_bf16(kf[1][1], qf1, s1, 0, 0, 0);

            float p00 = EXP2(s0[0]), p01 = EXP2(s0[1]);
            float p02 = EXP2(s0[2]), p03 = EXP2(s0[3]);
            float p10 = EXP2(s1[0]), p11 = EXP2(s1[1]);
            float p12 = EXP2(s1[2]), p13 = EXP2(s1[3]);
            rs += ((p00 + p01) + (p02 + p03)) + ((p10 + p11) + (p12 + p13));

            union { bf16x8 v; __hip_bfloat162 h2[4]; } pf;
            pf.h2[0] = __float22bfloat162_rn(make_float2(p00, p01));
            pf.h2[1] = __float22bfloat162_rn(make_float2(p02, p03));
            pf.h2[2] = __float22bfloat162_rn(make_float2(p10, p11));
            pf.h2[3] = __float22bfloat162_rn(make_float2(p12, p13));

            #pragma unroll
            for (int dt = 0; dt < 4; ++dt)
                oacc[dt] = __builtin_amdgcn_mfma_f32_16x16x32_bf16(vf[dt], pf.v, oacc[dt], 0, 0, 0);
        }
        __syncthreads();        // drains stage vmcnt + lgkm; buffers swap safe
        buf ^= 1;
    }

    // per-wave softmax denominator: sum quads for row l15
    rs += __shfl_xor(rs, 16);
    rs += __shfl_xor(rs, 32);
    const float linv = 1.0f / rs;

    // direct store: wave owns rows q0+wave*16+l15 completely (no merge)
    float* op = out + ((long)(b * S_LEN + q0 + wave * 16 + l15)) * 1024 + h * 64;
    #pragma unroll
    for (int dt = 0; dt < 4; ++dt) {
        f32x4 a = oacc[dt];
        *(float4*)(op + dt * 16 + quad * 4) =
            make_float4(a[0] * linv, a[1] * linv, a[2] * linv, a[3] * linv);
    }
}

extern "C" void kernel_launch(void* const* d_in, const int* in_sizes, int n_in,
                              void* d_out, int out_size, void* d_ws, size_t ws_size,
                              hipStream_t stream) {
    const float* kin = (const float*)d_in[0];
    const float* qin = (const float*)d_in[1];
    const float* vin = (const float*)d_in[2];
    const float* Wk  = (const float*)d_in[3];
    const float* Wq  = (const float*)d_in[4];
    const float* Wv  = (const float*)d_in[5];
    float* out = (float*)d_out;

    u16* wsp = (u16*)d_ws;
    u16* Kh = wsp;
    u16* Qh = wsp + (long)HEAD_ELEMS;
    u16* Vt = wsp + 2 * (long)HEAD_ELEMS;

    proj_fused<<<dim3(2048), 256, 0, stream>>>(kin, qin, vin, Wk, Wq, Wv, Kh, Qh, Vt);
    attn_kernel<<<dim3(1024), 256, 0, stream>>>(Qh, Kh, Vt, out);
}

// Round 11
// 145.843 us; speedup vs baseline: 1.0330x; 1.0330x over previous
//
#include <hip/hip_runtime.h>
#include <hip/hip_bf16.h>

typedef unsigned short u16;
typedef __bf16 bf16x8 __attribute__((ext_vector_type(8)));
typedef float f32x4 __attribute__((ext_vector_type(4)));

#define S_LEN 2048
#define NH 16
#define NB 2
#define HEAD_ELEMS (NB * NH * S_LEN * 64)
#define BH_ELEMS (S_LEN * 64)   // 131072 elems per (b,h)

#if __has_builtin(__builtin_amdgcn_exp2f)
#define EXP2(x) __builtin_amdgcn_exp2f(x)
#else
#define EXP2(x) exp2f(x)
#endif

// 1/sqrt(64) * log2(e), folded into Wq. Scores come out in log2 units.
#define QSCALE 0.180336880f
#define SHIFT2 30.0f

// async global->LDS, 16B per lane: LDS dest = uniform base + lane*16,
// global src = per-lane. Our Kp/Vt2 DRAM tiles are already lane-permuted,
// so the LDS image == DRAM tile and fragment reads stay lane-linear.
#define GLDS16(g, l) __builtin_amdgcn_global_load_lds( \
    (const __attribute__((address_space(1))) void*)(g), \
    (__attribute__((address_space(3))) void*)(l), 16, 0, 0)

__device__ __forceinline__ bf16x8 pack8(float4 a, float4 b, float sc) {
    union { bf16x8 v; __hip_bfloat162 h[4]; } r;
    r.h[0] = __float22bfloat162_rn(make_float2(a.x * sc, a.y * sc));
    r.h[1] = __float22bfloat162_rn(make_float2(a.z * sc, a.w * sc));
    r.h[2] = __float22bfloat162_rn(make_float2(b.x * sc, b.y * sc));
    r.h[3] = __float22bfloat162_rn(make_float2(b.z * sc, b.w * sc));
    return r.v;
}

// ---------------- fused projections (byte-identical to verified R9/R10) ----
__global__ __launch_bounds__(256) void proj_fused(
    const float* __restrict__ kin, const float* __restrict__ qin,
    const float* __restrict__ vin,
    const float* __restrict__ Wk, const float* __restrict__ Wq,
    const float* __restrict__ Wv,
    u16* __restrict__ Kh, u16* __restrict__ Qh, u16* __restrict__ Vt)
{
    __shared__ __align__(16) u16 Yld[8 * 16 * 72];   // kq uses all; v uses first 64*72
    __shared__ __align__(16) u16 Stage[16 * 512];    // kq x-tile 16KB; v uses first 8KB

    const int tid = threadIdx.x;
    const int wave = tid >> 6;
    const int lane = tid & 63;
    const int quad = lane >> 4;
    const int l15 = lane & 15;
    const int bid = blockIdx.x;

    if (bid < 1024) {
        // ---------------- K/Q projection ----------------
        const int stile = bid & 255;
        const int p = (bid >> 8) & 1;
        const int hh = bid >> 9;
        const long row0 = (long)stile * 16;
        const int b = (int)(row0 >> 11);
        const int s0 = (int)(row0 & 2047);

        const float* X = p ? qin : kin;
        const float* W = p ? Wq : Wk;
        const float sc = p ? QSCALE : 1.0f;

        // stage x: 16 rows x 512 cols (this hh half) -> bf16 LDS, swizzled.
        #pragma unroll
        for (int it = 0; it < 4; ++it) {
            int chunk = tid + it * 256;              // 0..1023
            int row = chunk >> 6, col8 = chunk & 63;
            const float* gp = X + (row0 + row) * 1024 + hh * 512 + col8 * 8;
            bf16x8 v = pack8(*(const float4*)gp, *(const float4*)(gp + 4), 1.0f);
            int byteoff = (row * 1024 + col8 * 16) ^ ((row & 7) << 4);
            *(bf16x8*)((char*)Stage + byteoff) = v;
        }

        bf16x8 wf[4][2];
        #pragma unroll
        for (int nt = 0; nt < 4; ++nt) {
            const float* wr = W + (nt * 16 + l15) * 64 + quad * 8;
            wf[nt][0] = pack8(*(const float4*)(wr),      *(const float4*)(wr + 4),  sc);
            wf[nt][1] = pack8(*(const float4*)(wr + 32), *(const float4*)(wr + 36), sc);
        }
        __syncthreads();

        #pragma unroll
        for (int hp = 0; hp < 2; ++hp) {
            const int hl = wave * 2 + hp;            // 0..7
            int acol = l15 * 1024 + hl * 128 + quad * 16;
            int swz = (l15 & 7) << 4;
            bf16x8 a0 = *(const bf16x8*)((const char*)Stage + (acol ^ swz));
            bf16x8 a1 = *(const bf16x8*)((const char*)Stage + ((acol + 64) ^ swz));
            #pragma unroll
            for (int nt = 0; nt < 4; ++nt) {
                f32x4 c = (f32x4){0.f, 0.f, 0.f, 0.f};
                c = __builtin_amdgcn_mfma_f32_16x16x32_bf16(a0, wf[nt][0], c, 0, 0, 0);
                c = __builtin_amdgcn_mfma_f32_16x16x32_bf16(a1, wf[nt][1], c, 0, 0, 0);
                union { __hip_bfloat162 h2; u16 u[2]; } x01, x23;
                x01.h2 = __float22bfloat162_rn(make_float2(c[0], c[1]));
                x23.h2 = __float22bfloat162_rn(make_float2(c[2], c[3]));
                int base = (hl * 16 + quad * 4) * 72 + nt * 16 + l15;
                Yld[base]       = x01.u[0];
                Yld[base + 72]  = x01.u[1];
                Yld[base + 144] = x23.u[0];
                Yld[base + 216] = x23.u[1];
            }
        }
        __syncthreads();

        if (p) {
            // Q: baseline row-major writes
            #pragma unroll
            for (int it = 0; it < 4; ++it) {
                int idx = tid + it * 256;            // 0..1023
                int eg = idx & 7, s = (idx >> 3) & 15, hl = idx >> 7;
                int bh = b * NH + hh * 8 + hl;
                *(float4*)(Qh + ((long)bh * S_LEN + s0 + s) * 64 + eg * 8) =
                    *(const float4*)&Yld[(hl * 16 + s) * 72 + eg * 8];
            }
        } else {
            // K: permuted Kp writes (16B chunk per thread, e contiguous)
            #pragma unroll
            for (int it = 0; it < 4; ++it) {
                int idx = tid + it * 256;            // 0..1023
                int eg = idx & 7, s = (idx >> 3) & 15, hl = idx >> 7;
                int bh = b * NH + hh * 8 + hl;
                int sg = s0 + s;                     // global s row within batch
                int kt = sg >> 6, c = (sg >> 5) & 1, rp = sg & 31;
                int nn = (rp >> 2) & 1;
                int l15p = ((rp >> 3) << 2) | (rp & 3);
                int j = eg >> 2, qd = eg & 3;
                long off = (long)bh * BH_ELEMS
                         + (long)((((kt * 2 + c) * 2 + nn) * 2 + j) * 512 + (qd * 16 + l15p) * 8);
                *(float4*)(Kh + off) = *(const float4*)&Yld[(hl * 16 + s) * 72 + eg * 8];
            }
        }
    } else {
        // ---------------- V projection (permuted Vt2 out) ----------------
        const int vid = bid - 1024;
        const long row0 = (long)(vid & 63) * 64;
        const int b = (int)(row0 >> 11);
        const int s0 = (int)(row0 & 2047);
        const int h = vid >> 6;
        const int bh = b * NH + h;
        const int kt = s0 >> 6;                      // this block covers exactly one kt tile

        #pragma unroll
        for (int it = 0; it < 4; ++it) {
            int chunk = tid + it * 256;              // 0..1023
            int row = chunk >> 4, c16 = chunk & 15;
            const float* gp = vin + (row0 + row) * 1024 + h * 64 + c16 * 4;
            float4 f = *(const float4*)gp;
            union { __hip_bfloat162 h2[2]; unsigned long long u; } pk;
            pk.h2[0] = __float22bfloat162_rn(make_float2(f.x, f.y));
            pk.h2[1] = __float22bfloat162_rn(make_float2(f.z, f.w));
            int byteoff = (row * 128 + c16 * 8) ^ ((row & 7) << 4);
            *(unsigned long long*)((char*)Stage + byteoff) = pk.u;
        }

        bf16x8 wf[4][2];
        #pragma unroll
        for (int dt = 0; dt < 4; ++dt) {
            const float* wr = Wv + (dt * 16 + l15) * 64 + quad * 8;
            wf[dt][0] = pack8(*(const float4*)(wr),      *(const float4*)(wr + 4),  1.0f);
            wf[dt][1] = pack8(*(const float4*)(wr + 32), *(const float4*)(wr + 36), 1.0f);
        }
        __syncthreads();

        int vcol = (wave * 16 + l15) * 128 + quad * 16;
        int vswz = (l15 & 7) << 4;
        bf16x8 x0 = *(const bf16x8*)((const char*)Stage + (vcol ^ vswz));
        bf16x8 x1 = *(const bf16x8*)((const char*)Stage + ((vcol + 64) ^ vswz));

        #pragma unroll
        for (int dt = 0; dt < 4; ++dt) {
            f32x4 c = (f32x4){0.f, 0.f, 0.f, 0.f};
            c = __builtin_amdgcn_mfma_f32_16x16x32_bf16(wf[dt][0], x0, c, 0, 0, 0);
            c = __builtin_amdgcn_mfma_f32_16x16x32_bf16(wf[dt][1], x1, c, 0, 0, 0);
            int base = (dt * 16 + quad * 4) * 72 + wave * 16 + l15;
            union { __hip_bfloat162 h2; u16 u[2]; } x01, x23;
            x01.h2 = __float22bfloat162_rn(make_float2(c[0], c[1]));
            x23.h2 = __float22bfloat162_rn(make_float2(c[2], c[3]));
            Yld[base]       = x01.u[0];
            Yld[base + 72]  = x01.u[1];
            Yld[base + 144] = x23.u[0];
            Yld[base + 216] = x23.u[1];
        }
        __syncthreads();

        u16* dstb = Vt + (long)bh * BH_ELEMS;
        #pragma unroll
        for (int it = 0; it < 2; ++it) {
            int idx = tid + it * 256;                // 0..511
            int sg = idx & 7, e_row = idx >> 3;
            int c = sg >> 2, lhi = sg & 3;
            int dt = e_row >> 4, l15p = e_row & 15;
            long off = (long)(((kt * 2 + c) * 4 + dt) * 512 + (lhi * 16 + l15p) * 8);
            *(float4*)(dstb + off) = *(const float4*)&Yld[e_row * 72 + sg * 8];
        }
    }
}

// ---------------- attention: shared-kt + gload_lds dbuf + g=2 amortization -
// R11 = R10 skeleton with each wave owning 32 q-rows (2 g-groups of 16):
//  - q-block 128 rows, grid 512 = exactly 2 blocks/CU (co-resident).
//  - Each kf/vf LDS read now feeds 2 MFMAs (was 1): LDS read traffic per CU
//    halves, 8MB->4MB (~96k->~48k cy vs 110k total: R10 was LDS-BW-bound).
//  - MFMA/SIMD unchanged (2 waves x 1024); pipes now balanced.
//  - Merge-free epilogue kept (wave owns its rows); XCD decode kept.
__global__ __launch_bounds__(256, 2) void attn_kernel(
    const u16* __restrict__ Qh, const u16* __restrict__ Kh,
    const u16* __restrict__ Vt, float* __restrict__ out)
{
    __shared__ __align__(16) u16 KV[2][8192];   // [buf][K 4096 elems | V 4096 elems]

    const int tid = threadIdx.x;
    const int wave = tid >> 6;
    const int lane = tid & 63;
    const int quad = lane >> 4;
    const int l15 = lane & 15;
    // XCD-aware bijective decode (512 blocks, 8 XCDs, 4 bh per XCD)
    const int bid = blockIdx.x;
    const int xcd = bid & 7;
    const int i = bid >> 3;                          // 0..63
    const int bh = xcd * 4 + (i >> 4);               // 4 bh per XCD
    const int qb = i & 15;                           // 16 q-tiles of 128
    const int b = bh >> 4, h = bh & 15;
    const int q0 = qb * 128;
    const u16* kb = Kh + (long)bh * BH_ELEMS;
    const u16* vb = Vt + (long)bh * BH_ELEMS;

    // Q fragments for this wave's 32 q-rows (2 groups of 16) -> registers
    bf16x8 qf[2][2];
    #pragma unroll
    for (int g = 0; g < 2; ++g) {
        const u16* qp = Qh + ((long)bh * S_LEN + q0 + wave * 32 + g * 16 + l15) * 64 + quad * 8;
        qf[g][0] = *(const bf16x8*)(qp);
        qf[g][1] = *(const bf16x8*)(qp + 32);
    }

    // staging split: waves 0/1 -> K halves, waves 2/3 -> V halves (4KB each)
    const u16* gsk = ((wave & 2) ? vb : kb) + ((wave & 1) << 11) + lane * 8;
    const int ldsoff = ((wave & 2) ? 4096 : 0) + ((wave & 1) << 11);

    f32x4 oacc[2][4];
    #pragma unroll
    for (int g = 0; g < 2; ++g)
        #pragma unroll
        for (int dt = 0; dt < 4; ++dt) oacc[g][dt] = (f32x4){0.f, 0.f, 0.f, 0.f};
    float rs[2] = {0.f, 0.f};

    // prologue: stage tile 0 into buf 0
    {
        const u16* g = gsk;
        u16* l = &KV[0][ldsoff];
        #pragma unroll
        for (int ii = 0; ii < 4; ++ii)
            GLDS16(g + ii * 512, l + ii * 512);
    }
    __syncthreads();

    int buf = 0;
    #pragma unroll 1
    for (int t = 0; t < S_LEN / 64; ++t) {
        if (t < S_LEN / 64 - 1) {                    // stage next tile -> buf^1
            const u16* g = gsk + (t + 1) * 4096;
            u16* l = &KV[buf ^ 1][ldsoff];
            #pragma unroll
            for (int ii = 0; ii < 4; ++ii)
                GLDS16(g + ii * 512, l + ii * 512);
        }

        const u16* Kl = &KV[buf][0];
        const u16* Vl = &KV[buf][4096];
        #pragma unroll
        for (int c = 0; c < 2; ++c) {
            bf16x8 kf[2][2], vf[4];
            #pragma unroll
            for (int nn = 0; nn < 2; ++nn) {
                kf[nn][0] = *(const bf16x8*)(Kl + ((c * 2 + nn) * 2 + 0) * 512 + lane * 8);
                kf[nn][1] = *(const bf16x8*)(Kl + ((c * 2 + nn) * 2 + 1) * 512 + lane * 8);
            }
            #pragma unroll
            for (int dt = 0; dt < 4; ++dt)
                vf[dt] = *(const bf16x8*)(Vl + (c * 4 + dt) * 512 + lane * 8);

            #pragma unroll
            for (int g = 0; g < 2; ++g) {
                f32x4 s0 = (f32x4){-SHIFT2, -SHIFT2, -SHIFT2, -SHIFT2};
                f32x4 s1 = (f32x4){-SHIFT2, -SHIFT2, -SHIFT2, -SHIFT2};
                s0 = __builtin_amdgcn_mfma_f32_16x16x32_bf16(kf[0][0], qf[g][0], s0, 0, 0, 0);
                s0 = __builtin_amdgcn_mfma_f32_16x16x32_bf16(kf[0][1], qf[g][1], s0, 0, 0, 0);
                s1 = __builtin_amdgcn_mfma_f32_16x16x32_bf16(kf[1][0], qf[g][0], s1, 0, 0, 0);
                s1 = __builtin_amdgcn_mfma_f32_16x16x32_bf16(kf[1][1], qf[g][1], s1, 0, 0, 0);

                float p00 = EXP2(s0[0]), p01 = EXP2(s0[1]);
                float p02 = EXP2(s0[2]), p03 = EXP2(s0[3]);
                float p10 = EXP2(s1[0]), p11 = EXP2(s1[1]);
                float p12 = EXP2(s1[2]), p13 = EXP2(s1[3]);
                rs[g] += ((p00 + p01) + (p02 + p03)) + ((p10 + p11) + (p12 + p13));

                union { bf16x8 v; __hip_bfloat162 h2[4]; } pf;
                pf.h2[0] = __float22bfloat162_rn(make_float2(p00, p01));
                pf.h2[1] = __float22bfloat162_rn(make_float2(p02, p03));
                pf.h2[2] = __float22bfloat162_rn(make_float2(p10, p11));
                pf.h2[3] = __float22bfloat162_rn(make_float2(p12, p13));

                #pragma unroll
                for (int dt = 0; dt < 4; ++dt)
                    oacc[g][dt] = __builtin_amdgcn_mfma_f32_16x16x32_bf16(vf[dt], pf.v, oacc[g][dt], 0, 0, 0);
            }
        }
        __syncthreads();        // drains stage vmcnt + lgkm; buffers swap safe
        buf ^= 1;
    }

    // per-wave softmax denominators: sum quads per g
    #pragma unroll
    for (int g = 0; g < 2; ++g) {
        rs[g] += __shfl_xor(rs[g], 16);
        rs[g] += __shfl_xor(rs[g], 32);
    }

    // direct store: wave owns rows q0+wave*32+g*16+l15 completely (no merge)
    #pragma unroll
    for (int g = 0; g < 2; ++g) {
        const float linv = 1.0f / rs[g];
        float* op = out + ((long)(b * S_LEN + q0 + wave * 32 + g * 16 + l15)) * 1024 + h * 64;
        #pragma unroll
        for (int dt = 0; dt < 4; ++dt) {
            f32x4 a = oacc[g][dt];
            *(float4*)(op + dt * 16 + quad * 4) =
                make_float4(a[0] * linv, a[1] * linv, a[2] * linv, a[3] * linv);
        }
    }
}

extern "C" void kernel_launch(void* const* d_in, const int* in_sizes, int n_in,
                              void* d_out, int out_size, void* d_ws, size_t ws_size,
                              hipStream_t stream) {
    const float* kin = (const float*)d_in[0];
    const float* qin = (const float*)d_in[1];
    const float* vin = (const float*)d_in[2];
    const float* Wk  = (const float*)d_in[3];
    const float* Wq  = (const float*)d_in[4];
    const float* Wv  = (const float*)d_in[5];
    float* out = (float*)d_out;

    u16* wsp = (u16*)d_ws;
    u16* Kh = wsp;
    u16* Qh = wsp + (long)HEAD_ELEMS;
    u16* Vt = wsp + 2 * (long)HEAD_ELEMS;

    proj_fused<<<dim3(2048), 256, 0, stream>>>(kin, qin, vin, Wk, Wq, Wv, Kh, Qh, Vt);
    attn_kernel<<<dim3(512), 256, 0, stream>>>(Qh, Kh, Vt, out);
}